// Round 13
// baseline (1178.624 us; speedup 1.0000x reference)
//
#include <hip/hip_runtime.h>
#include <stdint.h>

#define T_LEN 2048
#define B_TOT 64
#define N_TAG 128

typedef __attribute__((ext_vector_type(4))) float f32x4;
typedef __attribute__((ext_vector_type(4))) uint32_t u32x4;
typedef __attribute__((ext_vector_type(2))) uint16_t u16x2;
typedef __attribute__((ext_vector_type(8))) int i32x8;

template <int S>
struct IC {
  static constexpr int value = S;
};

// pack two fp32 -> dword of two bf16 (round-half-up); elem0 in low half
__device__ __forceinline__ uint32_t pack2_bf16(float a, float b) {
  uint32_t ua = __float_as_uint(a) + 0x8000u;
  uint32_t ub = __float_as_uint(b) + 0x8000u;
  return __builtin_amdgcn_perm(ua, ub, 0x03020706u);
}
__device__ __forceinline__ float bf_lo(uint32_t w) {
  return __uint_as_float(w << 16);
}
__device__ __forceinline__ float bf_hi(uint32_t w) {
  return __uint_as_float(w & 0xffff0000u);
}
// pack 4 fp32 -> 4 fp8 e4m3 (OCP), bytes 0..3 = a,b,c,d
__device__ __forceinline__ uint32_t pack4_fp8(float a, float b, float c,
                                              float d) {
  int v = __builtin_amdgcn_cvt_pk_fp8_f32(a, b, 0, false);
  v = __builtin_amdgcn_cvt_pk_fp8_f32(c, d, v, true);
  return (uint32_t)v;
}
// pack 4 fp32 -> 4 bf8 e5m2 (OCP), bytes 0..3 = a,b,c,d
__device__ __forceinline__ uint32_t pack4_bf8(float a, float b, float c,
                                              float d) {
  int v = __builtin_amdgcn_cvt_pk_bf8_f32(a, b, 0, false);
  v = __builtin_amdgcn_cvt_pk_bf8_f32(c, d, v, true);
  return (uint32_t)v;
}
// per-u16 add (v_pk_add_u16): exact 2^-D on a packed bf16 pair via exponent
__device__ __forceinline__ uint32_t pkadd_u16(uint32_t a, uint32_t b) {
  u16x2 x = __builtin_bit_cast(u16x2, a);
  u16x2 y = __builtin_bit_cast(u16x2, b);
  x = x + y;
  return __builtin_bit_cast(uint32_t, x);
}

// prepass: ws[t][b][j] = bf16(exp(em[b][t][j])), j-pairs packed in u32
__global__ __launch_bounds__(256) void eem_prepass(const float* __restrict__ em,
                                                   uint32_t* __restrict__ ws) {
  const int tid = blockIdx.x * blockDim.x + threadIdx.x;  // 0 .. 2^21-1
  const int b = tid >> 15;
  const int rem = tid & 32767;
  const int t = rem >> 4;
  const int kk = rem & 15;  // 8 floats per thread
  const float4* src =
      (const float4*)(em + ((size_t)b * T_LEN + t) * N_TAG + kk * 8);
  const float4 p0 = src[0];
  const float4 p1 = src[1];
  u32x4 o;
  o[0] = pack2_bf16(__expf(p0.x), __expf(p0.y));
  o[1] = pack2_bf16(__expf(p0.z), __expf(p0.w));
  o[2] = pack2_bf16(__expf(p1.x), __expf(p1.y));
  o[3] = pack2_bf16(__expf(p1.z), __expf(p1.w));
  *(u32x4*)(ws + ((size_t)t * B_TOT + b) * (N_TAG / 2) + kk * 4) = o;
}

// 4 blocks x 64 threads: ONE WAVE owns a 16-batch group's ENTIRE state.
// 8 independent mfma_scale_f32_16x16x128_f8f6f4 per step (A=E e4m3 per
// j-tile, B = bf8 state in this wave's own registers, unit scales --
// validated R11). A-row permutation j = 32*(m>>2) + 4*jt + (m&3) makes
// lane (q,c)'s D output (tile jt, reg r) = j = 32q+4jt+r = byte r of
// B-dword jt of the SAME lane: the D->B roundtrip is lane-local.
// NO LDS, NO barrier, no cross-wave traffic. Only cross-lane op: one
// __shfl broadcast of the damped rescale exponent (1-step lag, R10/R11
// controller: D=(e>>1)+3, clamp +-40; exact L bookkeeping; state clamp
// 16384 before saturating bf8 cvt). eem pre-exponentiated bf16 (L3-hot),
// lane (q,c) reads its 32 consecutive j in 4 contiguous dwordx4.
__global__ __launch_bounds__(64, 1) void crf_fwd_kernel(
    const float* __restrict__ em, const int* __restrict__ lens,
    const float* __restrict__ trans, const float* __restrict__ head,
    const float* __restrict__ last, const uint32_t* __restrict__ eem,
    float* __restrict__ out) {
  const int lane = threadIdx.x & 63;
  const int c = lane & 15;  // batch-in-tile (B/D col)
  const int q = lane >> 4;
  const int bg = (int)blockIdx.x * 16 + c;

  // A operands (fp8 e4m3), one per j-tile jt:
  // lane (q, m=c), dword pd byte b -> k = 32q + 4pd + b,
  // value = exp(trans[k][jA]), jA = 32*(c>>2) + 4*jt + (c&3)
  i32x8 aop[8];
#pragma unroll
  for (int jt = 0; jt < 8; ++jt) {
    const int jA = 32 * (c >> 2) + 4 * jt + (c & 3);
#pragma unroll
    for (int pd = 0; pd < 8; ++pd) {
      const int k0 = 32 * q + 4 * pd;
      aop[jt][pd] = (int)pack4_fp8(__expf(trans[(k0 + 0) * N_TAG + jA]),
                                   __expf(trans[(k0 + 1) * N_TAG + jA]),
                                   __expf(trans[(k0 + 2) * N_TAG + jA]),
                                   __expf(trans[(k0 + 3) * N_TAG + jA]));
    }
  }

  // lane's 32 j's: j = 32q + 4jt + r
  float lastx[32];
#pragma unroll
  for (int jt = 0; jt < 8; ++jt)
#pragma unroll
    for (int r = 0; r < 4; ++r)
      lastx[4 * jt + r] = __expf(last[32 * q + 4 * jt + r]);

  const int len = lens[bg];
  float L = 0.f, Lcap = 0.f;

  // initial state in B-operand registers: bop[jt] byte r = bf8(S0[j]),
  // j = 32q + 4jt + r, S0 = e^{head + em[.,0,.]}
  const float* emb = em + (size_t)bg * T_LEN * N_TAG;
  i32x8 bop;
  {
    float cap0 = 0.f;
#pragma unroll
    for (int jt = 0; jt < 8; ++jt) {
      float v[4];
#pragma unroll
      for (int r = 0; r < 4; ++r) {
        const int j = 32 * q + 4 * jt + r;
        v[r] = __expf(head[j] + emb[j]);
        cap0 += v[r] * lastx[4 * jt + r];
      }
      bop[jt] = (int)pack4_bf8(v[0], v[1], v[2], v[3]);
    }
    if (len == 1) {  // edge (setup guarantees len>=1024; keep correct)
      cap0 += __shfl_xor(cap0, 16);
      cap0 += __shfl_xor(cap0, 32);
      if (q == 0) out[bg] = __logf(cap0);
    }
  }

  // eem prefetch: slot t&3 holds row t, this lane's 32 bf16 (contiguous)
  const uint32_t* eemb = eem + (size_t)bg * 64 + 16 * q;
  u32x4 eslot[4][4];
  auto issue_eem = [&](auto sc, int row) {
    constexpr int S = decltype(sc)::value;
    const u32x4* p = (const u32x4*)(eemb + (size_t)row * 4096);
    eslot[S][0] = p[0];
    eslot[S][1] = p[1];
    eslot[S][2] = p[2];
    eslot[S][3] = p[3];
  };
  issue_eem(IC<1>{}, 1);
  issue_eem(IC<2>{}, 2);
  issue_eem(IC<3>{}, 3);

  const f32x4 vzero = {0.f, 0.f, 0.f, 0.f};
  int D = 3;  // rescale exponent applied this step (damped controller)

  auto step = [&](auto slotc, int t) {
    constexpr int SLOT = decltype(slotc)::value;
    // prefetch row t+3 into the slot freed last step
    {
      int row = t + 3;
      if (row > T_LEN - 1) row = T_LEN - 1;
      issue_eem(IC<(SLOT + 3) & 3>{}, row);
    }
    // exact 2^-D on packed bf16 eem (exponent-field add; ranges safe)
    const uint32_t dadd = (((uint32_t)(-D) << 7) & 0xffffu) * 0x00010001u;
    uint32_t evs[16];
#pragma unroll
    for (int g = 0; g < 4; ++g)
#pragma unroll
      for (int k = 0; k < 4; ++k)
        evs[4 * g + k] = pkadd_u16(eslot[SLOT][g][k], dadd);
    L += (float)D * 0.6931471805599453f;
    // 8 independent K=128 MX MFMAs (A e4m3 cbsz=0, B bf8 blgp=1, unit scales)
    f32x4 acc[8];
#pragma unroll
    for (int jt = 0; jt < 8; ++jt)
      acc[jt] = __builtin_amdgcn_mfma_scale_f32_16x16x128_f8f6f4(
          aop[jt], bop, vzero, 0, 1, 0, 0x7f7f7f7f, 0, 0x7f7f7f7f);
    // epilogue: st = acc * (eem*2^-D); capture (rare); clamp+pack -> bop
    float st[32];
#pragma unroll
    for (int jt = 0; jt < 8; ++jt) {
      const uint32_t e0 = evs[2 * jt];
      const uint32_t e1 = evs[2 * jt + 1];
      st[4 * jt + 0] = acc[jt][0] * bf_lo(e0);
      st[4 * jt + 1] = acc[jt][1] * bf_hi(e0);
      st[4 * jt + 2] = acc[jt][2] * bf_lo(e1);
      st[4 * jt + 3] = acc[jt][3] * bf_hi(e1);
    }
    if (t == len - 1) {  // divergent-rare capture
      float s = 0.f;
#pragma unroll
      for (int i = 0; i < 32; ++i) s += st[i] * lastx[i];
      s += __shfl_xor(s, 16);
      s += __shfl_xor(s, 32);
      if (q == 0) out[bg] = __logf(s) + L;
      (void)Lcap;
    }
    // damped probe of j=0 (held by lane c: q=0, jt=0, r=0); 1-step lag
    {
      int e = (int)(__float_as_uint(acc[0][0]) >> 23) - 127;
      e = e < -40 ? -40 : (e > 40 ? 40 : e);
      const int eraw = (e >> 1) + 3;  // half-gain: z^2 = z - 1/2, damped
      D = __shfl(eraw, c);
    }
#pragma unroll
    for (int jt = 0; jt < 8; ++jt) {
      bop[jt] = (int)pack4_bf8(fminf(st[4 * jt + 0], 16384.f),
                               fminf(st[4 * jt + 1], 16384.f),
                               fminf(st[4 * jt + 2], 16384.f),
                               fminf(st[4 * jt + 3], 16384.f));
    }
  };

  int t = 1;
#pragma unroll 1
  for (int it = 0; it < 511; ++it) {  // t = 1 .. 2044
    step(IC<1>{}, t);
    step(IC<2>{}, t + 1);
    step(IC<3>{}, t + 2);
    step(IC<0>{}, t + 3);
    t += 4;
  }
  step(IC<1>{}, t);      // 2045
  step(IC<2>{}, t + 1);  // 2046
  step(IC<3>{}, t + 2);  // 2047
}

extern "C" void kernel_launch(void* const* d_in, const int* in_sizes, int n_in,
                              void* d_out, int out_size, void* d_ws,
                              size_t ws_size, hipStream_t stream) {
  const float* em = (const float*)d_in[0];
  const int* lens = (const int*)d_in[1];
  const float* trans = (const float*)d_in[2];
  const float* head = (const float*)d_in[3];
  const float* last = (const float*)d_in[4];
  float* out = (float*)d_out;
  uint32_t* ws = (uint32_t*)d_ws;  // 2048*64*128 bf16 = 32 MiB

  eem_prepass<<<8192, 256, 0, stream>>>(em, ws);
  crf_fwd_kernel<<<4, 64, 0, stream>>>(em, lens, trans, head, last, ws, out);
}